// Round 1
// baseline (120.634 us; speedup 1.0000x reference)
//
#include <hip/hip_runtime.h>

#define MROWS 512
#define NCOLS 8192
#define NVALS 4096
#define BLOCK 256
#define NWAVES (BLOCK / 64)
#define EPSF 1e-10f

__global__ __launch_bounds__(BLOCK) void listmle_row_kernel(
    const float* __restrict__ outputs,
    const float* __restrict__ runtime,
    const int*   __restrict__ idxs,
    float* __restrict__ row_out)
{
    __shared__ int minidx[NVALS];                 // 16 KB
    __shared__ unsigned long long keys[NVALS];    // 32 KB
    __shared__ float evals[NVALS];                // 16 KB
    __shared__ float red_f[NWAVES];
    __shared__ float red_f2[NWAVES];
    __shared__ float wave_tot[NWAVES];
    __shared__ float s_scan[BLOCK];               // 1 KB
    __shared__ int kcount;

    const int row = blockIdx.x;
    const int tid = threadIdx.x;
    const int lane = tid & 63;
    const int wave = tid >> 6;

    const float* row_pred = outputs + (size_t)row * NCOLS;
    const float* row_rt   = runtime + (size_t)row * NCOLS;
    const int*   row_idx  = idxs    + (size_t)row * NCOLS;

    // ---- 1. init ----
    for (int v = tid; v < NVALS; v += BLOCK) minidx[v] = 0x7FFFFFFF;
    if (tid == 0) kcount = 0;
    __syncthreads();

    // ---- 2. first-occurrence per value (stable-argsort dedup semantics) ----
    for (int j = tid; j < NCOLS; j += BLOCK)
        atomicMin(&minidx[row_idx[j]], j);
    __syncthreads();

    // ---- 3. gather kept entries; local max/sum of preds ----
    float lmax = -INFINITY;
    float lsum = 0.f;
    for (int j = tid; j < NCOLS; j += BLOCK) {
        int v = row_idx[j];
        if (minidx[v] == j) {
            float p = row_pred[j];
            lmax = fmaxf(lmax, p);
            lsum += p;
            int slot = atomicAdd(&kcount, 1);
            unsigned int kb = __float_as_uint(row_rt[j]);  // >=0 floats: uint order == float order
            keys[slot]  = ((unsigned long long)kb << 32) | (unsigned int)slot;
            evals[slot] = p;   // temporarily store pred; converted to exp below
        }
    }
    // block reduce max & sum
    for (int off = 32; off > 0; off >>= 1) {
        lmax = fmaxf(lmax, __shfl_down(lmax, off));
        lsum += __shfl_down(lsum, off);
    }
    if (lane == 0) { red_f[wave] = lmax; red_f2[wave] = lsum; }
    __syncthreads();
    float mx = red_f[0], sumpred = red_f2[0];
    for (int w = 1; w < NWAVES; ++w) {
        mx = fmaxf(mx, red_f[w]);
        sumpred += red_f2[w];
    }
    const int K = kcount;

    // ---- 4. pad keys; convert preds -> exp(pred - mx) ----
    for (int s = K + tid; s < NVALS; s += BLOCK)
        keys[s] = 0xFFFFFFFFFFFFFFFFULL;
    for (int s = tid; s < K; s += BLOCK)
        evals[s] = __expf(evals[s] - mx);
    __syncthreads();

    // ---- 5. bitonic sort of 4096 u64 keys, ascending ----
    for (int k = 2; k <= NVALS; k <<= 1) {
        for (int jj = k >> 1; jj > 0; jj >>= 1) {
            for (int t = tid; t < NVALS / 2; t += BLOCK) {
                int low = t & (jj - 1);
                int i = ((t ^ low) << 1) | low;   // (t & ~(jj-1))*2 + low
                int p = i | jj;
                unsigned long long a = keys[i];
                unsigned long long b = keys[p];
                bool up = ((i & k) == 0);
                if ((a > b) == up) { keys[i] = b; keys[p] = a; }
            }
            __syncthreads();
        }
    }

    // ---- 6. inclusive prefix scan of exps in sorted order; sum of logs ----
    constexpr int PER = NVALS / BLOCK;  // 16
    float vals[PER];
    float run = 0.f;
    const int base = tid * PER;
    for (int q = 0; q < PER; ++q) {
        int p = base + q;
        float e = 0.f;
        if (p < K) {
            int slot = (int)(keys[p] & 0xFFFFFFFFu);
            e = evals[slot];
        }
        run += e;
        vals[q] = run;
    }
    s_scan[tid] = run;
    __syncthreads();

    float x = s_scan[tid];
    for (int off = 1; off < 64; off <<= 1) {
        float y = __shfl_up(x, off);
        if (lane >= off) x += y;
    }
    if (lane == 63) wave_tot[wave] = x;
    __syncthreads();
    float woff = 0.f;
    for (int w = 0; w < wave; ++w) woff += wave_tot[w];
    const float excl = x - run + woff;   // exclusive prefix for this thread's chunk

    float logacc = 0.f;
    for (int q = 0; q < PER; ++q) {
        int p = base + q;
        if (p < K) logacc += __logf(excl + vals[q] + EPSF);
    }
    for (int off = 32; off > 0; off >>= 1)
        logacc += __shfl_down(logacc, off);
    if (lane == 0) red_f[wave] = logacc;   // safe: barriers since last read
    __syncthreads();

    if (tid == 0) {
        float tot = 0.f;
        for (int w = 0; w < NWAVES; ++w) tot += red_f[w];
        row_out[row] = tot - sumpred + (float)K * mx;
    }
}

__global__ __launch_bounds__(256) void listmle_finalize(
    const float* __restrict__ row_out, float* __restrict__ out)
{
    __shared__ double red_d[4];
    int tid = threadIdx.x;
    int lane = tid & 63, wave = tid >> 6;
    double acc = 0.0;
    for (int r = tid; r < MROWS; r += 256) acc += (double)row_out[r];
    for (int off = 32; off > 0; off >>= 1) acc += __shfl_down(acc, off);
    if (lane == 0) red_d[wave] = acc;
    __syncthreads();
    if (tid == 0) {
        double tot = 0.0;
        for (int w = 0; w < 4; ++w) tot += red_d[w];
        out[0] = (float)(tot / (double)MROWS);
    }
}

extern "C" void kernel_launch(void* const* d_in, const int* in_sizes, int n_in,
                              void* d_out, int out_size, void* d_ws, size_t ws_size,
                              hipStream_t stream) {
    const float* outputs = (const float*)d_in[0];
    const float* runtime = (const float*)d_in[1];
    const int*   idxs    = (const int*)d_in[2];
    float* out = (float*)d_out;
    float* ws  = (float*)d_ws;

    listmle_row_kernel<<<MROWS, BLOCK, 0, stream>>>(outputs, runtime, idxs, ws);
    listmle_finalize<<<1, 256, 0, stream>>>(ws, out);
}

// Round 2
// 37.008 us; speedup vs baseline: 3.2596x; 3.2596x over previous
//
#include <hip/hip_runtime.h>

#define MROWS 512
#define NCOLS 8192
#define NVALS 4096
#define BLOCK 256
#define NWAVES 4
#define EPSF 1e-10f

__global__ __launch_bounds__(BLOCK, 2) void listmle_row_kernel(
    const float* __restrict__ outputs,
    const float* __restrict__ runtime,
    const int*   __restrict__ idxs,
    float* __restrict__ row_out)
{
    // LDS: 4*16KB + 8KB + small = ~72.2KB -> 2 blocks/CU
    __shared__ unsigned int ksrc[NVALS];
    __shared__ unsigned int psrc[NVALS];
    __shared__ unsigned int kdst[NVALS];   // phase A: minidx (aliased)
    __shared__ unsigned int pdst[NVALS];
    __shared__ __align__(16) unsigned short hist[NVALS];  // 16 digits x 256 threads
    __shared__ float s_red[NWAVES];
    __shared__ float s_red2[NWAVES];
    __shared__ unsigned int s_cnt[NWAVES];

    const int tid  = threadIdx.x;
    const int lane = tid & 63;
    const int wave = tid >> 6;
    const int row  = blockIdx.x;

    const float* row_pred = outputs + (size_t)row * NCOLS;
    const float* row_rt   = runtime + (size_t)row * NCOLS;
    const int*   row_idx  = idxs    + (size_t)row * NCOLS;

    // ---- load 32 items/thread via 16B vectors; item m at column j(m) = (m>>2)*1024 + tid*4 + (m&3)
    int vidx[32]; float vpred[32]; float vrt[32];
    #pragma unroll
    for (int q = 0; q < 8; ++q) {
        const int base = (q << 10) + (tid << 2);
        int4   i4 = *reinterpret_cast<const int4*>(row_idx + base);
        float4 p4 = *reinterpret_cast<const float4*>(row_pred + base);
        float4 r4 = *reinterpret_cast<const float4*>(row_rt + base);
        vidx[q*4+0]=i4.x;  vidx[q*4+1]=i4.y;  vidx[q*4+2]=i4.z;  vidx[q*4+3]=i4.w;
        vpred[q*4+0]=p4.x; vpred[q*4+1]=p4.y; vpred[q*4+2]=p4.z; vpred[q*4+3]=p4.w;
        vrt[q*4+0]=r4.x;   vrt[q*4+1]=r4.y;   vrt[q*4+2]=r4.z;   vrt[q*4+3]=r4.w;
    }

    // ---- init minidx (kdst alias) ----
    #pragma unroll
    for (int i = 0; i < 16; ++i) kdst[i*256 + tid] = 0xFFFFFFFFu;
    __syncthreads();

    // ---- dedup: first occurrence (min j) per value; also max over ALL preds ----
    float lmax = -INFINITY;
    #pragma unroll
    for (int m = 0; m < 32; ++m) {
        const int j = ((m >> 2) << 10) + (tid << 2) + (m & 3);
        atomicMin(&kdst[vidx[m]], (unsigned)j);
        lmax = fmaxf(lmax, vpred[m]);
    }
    __syncthreads();

    // ---- kept mask + count ----
    unsigned kept = 0, mycnt = 0;
    #pragma unroll
    for (int m = 0; m < 32; ++m) {
        const int j = ((m >> 2) << 10) + (tid << 2) + (m & 3);
        if (kdst[vidx[m]] == (unsigned)j) { kept |= (1u << m); ++mycnt; }
    }

    // ---- block reduce lmax; block inclusive scan of mycnt (deterministic slots) ----
    #pragma unroll
    for (int off = 32; off > 0; off >>= 1) lmax = fmaxf(lmax, __shfl_down(lmax, off));
    if (lane == 0) s_red[wave] = lmax;
    unsigned xs = mycnt;
    #pragma unroll
    for (int off = 1; off < 64; off <<= 1) { unsigned y = __shfl_up(xs, off); if (lane >= off) xs += y; }
    if (lane == 63) s_cnt[wave] = xs;
    __syncthreads();
    const float mx = fmaxf(fmaxf(s_red[0], s_red[1]), fmaxf(s_red[2], s_red[3]));
    unsigned wb = 0;
    #pragma unroll
    for (int w = 0; w < NWAVES; ++w) if (w < wave) wb += s_cnt[w];
    const int K = (int)(s_cnt[0] + s_cnt[1] + s_cnt[2] + s_cnt[3]);
    unsigned slot = wb + xs - mycnt;   // exclusive base, thread-major order

    // ---- default-init items (pads: key=max, payload exp=0) ----
    #pragma unroll
    for (int i = 0; i < 16; ++i) { ksrc[i*256 + tid] = 0xFFFFFFFFu; psrc[i*256 + tid] = 0u; }
    __syncthreads();

    // ---- gather kept items into virtual layout phi(v)=(v&15)*256+(v>>4) ----
    float psum = 0.f;
    #pragma unroll
    for (int m = 0; m < 32; ++m) {
        if (kept & (1u << m)) {
            const float p = vpred[m];
            psum += p;
            const float e = __expf(p - mx);
            unsigned u = (unsigned)(vrt[m] * 16777216.0f);   // exact 24-bit monotone key
            u = (u > 0xFFFFFFu) ? 0xFFFFFFu : u;
            const int v  = (int)slot;
            const int ph = ((v & 15) << 8) | (v >> 4);
            ksrc[ph] = u;
            psrc[ph] = __float_as_uint(e);
            ++slot;
        }
    }
    #pragma unroll
    for (int off = 32; off > 0; off >>= 1) psum += __shfl_down(psum, off);
    if (lane == 0) s_red2[wave] = psum;
    __syncthreads();
    const float sumpred = s_red2[0] + s_red2[1] + s_red2[2] + s_red2[3];

    // ---- 6 stable LSD radix passes on 24-bit key (4 bits/pass) ----
#define RADIX_PASS(SHIFT, SK, SP, DK, DP)                                           \
    {                                                                               \
        uint4* h4 = reinterpret_cast<uint4*>(hist);                                 \
        h4[tid]       = make_uint4(0,0,0,0);                                        \
        h4[tid + 256] = make_uint4(0,0,0,0);                                        \
        __syncthreads();                                                            \
        unsigned kreg[16];                                                          \
        unsigned long long clo = 0ull, chi = 0ull;                                  \
        _Pragma("unroll")                                                           \
        for (int i = 0; i < 16; ++i) {                                              \
            const unsigned k = SK[i*256 + tid];                                     \
            kreg[i] = k;                                                            \
            const int d = (int)((k >> (SHIFT)) & 15u);                              \
            const unsigned long long inc = 1ull << ((d & 7) * 8);                   \
            if (d & 8) chi += inc; else clo += inc;                                 \
        }                                                                           \
        _Pragma("unroll")                                                           \
        for (int d = 0; d < 8; ++d) {                                               \
            hist[d*256 + tid]     = (unsigned short)((clo >> (d*8)) & 0xFFull);     \
            hist[(d+8)*256 + tid] = (unsigned short)((chi >> (d*8)) & 0xFFull);     \
        }                                                                           \
        __syncthreads();                                                            \
        uint4 ha = h4[tid*2], hb = h4[tid*2+1];                                     \
        unsigned w0[8] = {ha.x,ha.y,ha.z,ha.w,hb.x,hb.y,hb.z,hb.w};                 \
        unsigned runc = 0; unsigned exv[16];                                        \
        _Pragma("unroll")                                                           \
        for (int i = 0; i < 8; ++i) {                                               \
            const unsigned lo = w0[i] & 0xFFFFu, hi = w0[i] >> 16;                  \
            exv[2*i]   = runc; runc += lo;                                          \
            exv[2*i+1] = runc; runc += hi;                                          \
        }                                                                           \
        unsigned xc = runc;                                                         \
        _Pragma("unroll")                                                           \
        for (int off = 1; off < 64; off <<= 1) {                                    \
            const unsigned y = __shfl_up(xc, off); if (lane >= off) xc += y;        \
        }                                                                           \
        if (lane == 63) s_cnt[wave] = xc;                                           \
        __syncthreads();                                                            \
        unsigned cb = xc - runc;                                                    \
        _Pragma("unroll")                                                           \
        for (int w = 0; w < NWAVES; ++w) if (w < wave) cb += s_cnt[w];              \
        _Pragma("unroll")                                                           \
        for (int i = 0; i < 8; ++i)                                                 \
            w0[i] = ((exv[2*i] + cb) & 0xFFFFu) | ((exv[2*i+1] + cb) << 16);        \
        h4[tid*2]   = make_uint4(w0[0],w0[1],w0[2],w0[3]);                          \
        h4[tid*2+1] = make_uint4(w0[4],w0[5],w0[6],w0[7]);                          \
        __syncthreads();                                                            \
        unsigned long long rlo = 0ull, rhi = 0ull;                                  \
        _Pragma("unroll")                                                           \
        for (int i = 0; i < 16; ++i) {                                              \
            const unsigned k = kreg[i];                                             \
            const int d  = (int)((k >> (SHIFT)) & 15u);                             \
            const int sh = (d & 7) * 8;                                             \
            unsigned prior;                                                         \
            if (d & 8) { prior = (unsigned)((rhi >> sh) & 0xFFull); rhi += 1ull << sh; } \
            else       { prior = (unsigned)((rlo >> sh) & 0xFFull); rlo += 1ull << sh; } \
            const int r  = (int)hist[d*256 + tid] + (int)prior;                     \
            const int ph = ((r & 15) << 8) | (r >> 4);                              \
            DK[ph] = k;                                                             \
            DP[ph] = SP[i*256 + tid];                                               \
        }                                                                           \
        __syncthreads();                                                            \
    }

    RADIX_PASS(0,  ksrc, psrc, kdst, pdst)
    RADIX_PASS(4,  kdst, pdst, ksrc, psrc)
    RADIX_PASS(8,  ksrc, psrc, kdst, pdst)
    RADIX_PASS(12, kdst, pdst, ksrc, psrc)
    RADIX_PASS(16, ksrc, psrc, kdst, pdst)
    RADIX_PASS(20, kdst, pdst, ksrc, psrc)
#undef RADIX_PASS

    // ---- inclusive prefix scan of exps in sorted (virtual) order; sum of logs ----
    float vals[16]; float runf = 0.f;
    #pragma unroll
    for (int i = 0; i < 16; ++i) {
        runf += __uint_as_float(psrc[i*256 + tid]);   // pads carry 0.0f
        vals[i] = runf;
    }
    float xf = runf;
    #pragma unroll
    for (int off = 1; off < 64; off <<= 1) { const float y = __shfl_up(xf, off); if (lane >= off) xf += y; }
    if (lane == 63) s_red[wave] = xf;
    __syncthreads();
    float excl = xf - runf;
    #pragma unroll
    for (int w = 0; w < NWAVES; ++w) if (w < wave) excl += s_red[w];

    float logacc = 0.f;
    #pragma unroll
    for (int i = 0; i < 16; ++i) {
        if (tid*16 + i < K) logacc += __logf(excl + vals[i] + EPSF);
    }
    #pragma unroll
    for (int off = 32; off > 0; off >>= 1) logacc += __shfl_down(logacc, off);
    if (lane == 0) s_red2[wave] = logacc;
    __syncthreads();

    if (tid == 0) {
        const float tot = s_red2[0] + s_red2[1] + s_red2[2] + s_red2[3];
        row_out[row] = tot - sumpred + (float)K * mx;
    }
}

__global__ __launch_bounds__(256) void listmle_finalize(
    const float* __restrict__ row_out, float* __restrict__ out)
{
    __shared__ double red_d[4];
    const int tid = threadIdx.x;
    const int lane = tid & 63, wave = tid >> 6;
    double acc = 0.0;
    for (int r = tid; r < MROWS; r += 256) acc += (double)row_out[r];
    #pragma unroll
    for (int off = 32; off > 0; off >>= 1) acc += __shfl_down(acc, off);
    if (lane == 0) red_d[wave] = acc;
    __syncthreads();
    if (tid == 0) {
        double tot = 0.0;
        for (int w = 0; w < 4; ++w) tot += red_d[w];
        out[0] = (float)(tot / (double)MROWS);
    }
}

extern "C" void kernel_launch(void* const* d_in, const int* in_sizes, int n_in,
                              void* d_out, int out_size, void* d_ws, size_t ws_size,
                              hipStream_t stream) {
    const float* outputs = (const float*)d_in[0];
    const float* runtime = (const float*)d_in[1];
    const int*   idxs    = (const int*)d_in[2];
    float* out = (float*)d_out;
    float* ws  = (float*)d_ws;

    listmle_row_kernel<<<MROWS, BLOCK, 0, stream>>>(outputs, runtime, idxs, ws);
    listmle_finalize<<<1, 256, 0, stream>>>(ws, out);
}

// Round 3
// 35.214 us; speedup vs baseline: 3.4258x; 1.0510x over previous
//
#include <hip/hip_runtime.h>

#define MROWS 512
#define NCOLS 8192
#define NVALS 4096
#define BLOCK 512
#define NWAVES 8
#define EPSF 1e-10f

typedef unsigned long long u64;
typedef unsigned int u32;
typedef unsigned short u16;

__global__ __launch_bounds__(BLOCK, 4) void listmle_row_kernel(
    const float* __restrict__ outputs,
    const float* __restrict__ runtime,
    const int*   __restrict__ idxs,
    float* __restrict__ row_out)
{
    // 32KB sort array (u64 key|payload) + 16KB hist + 128B scratch = 48.1KB
    __shared__ __align__(16) unsigned char smem[32768 + 16384 + 128];
    u64* arr     = reinterpret_cast<u64*>(smem);                 // [4096]
    u32* minidx  = reinterpret_cast<u32*>(smem);                 // alias arr
    u16* hist    = reinterpret_cast<u16*>(smem + 32768);         // [16][512]
    u32* scr_u   = reinterpret_cast<u32*>(smem + 49152);         // [8]
    float* scr_f = reinterpret_cast<float*>(smem + 49152 + 32);  // [8]
    float* scr_f2= reinterpret_cast<float*>(smem + 49152 + 64);  // [8]

    const int tid  = threadIdx.x;
    const int lane = tid & 63;
    const int wave = tid >> 6;
    const int row  = blockIdx.x;

    const float* row_pred = outputs + (size_t)row * NCOLS;
    const float* row_rt   = runtime + (size_t)row * NCOLS;
    const int*   row_idx  = idxs    + (size_t)row * NCOLS;

    // ---- P1: load idx (16/thread, int4); init minidx ----
    int vidx[16];
    #pragma unroll
    for (int q = 0; q < 4; ++q) {
        int4 i4 = *reinterpret_cast<const int4*>(row_idx + (q << 11) + (tid << 2));
        vidx[q*4+0] = i4.x; vidx[q*4+1] = i4.y; vidx[q*4+2] = i4.z; vidx[q*4+3] = i4.w;
    }
    #pragma unroll
    for (int i = 0; i < 8; ++i) minidx[(i << 9) + tid] = 0xFFFFFFFFu;
    __syncthreads();

    // ---- P2: first-occurrence dedup (min column index per value) ----
    #pragma unroll
    for (int m = 0; m < 16; ++m) {
        const u32 j = ((m >> 2) << 11) + (tid << 2) + (m & 3);
        atomicMin(&minidx[vidx[m]], j);
    }
    __syncthreads();

    // ---- P3: kept mask + max over all preds (preds stay in regs) ----
    float vpred[16];
    #pragma unroll
    for (int q = 0; q < 4; ++q) {
        float4 p4 = *reinterpret_cast<const float4*>(row_pred + (q << 11) + (tid << 2));
        vpred[q*4+0] = p4.x; vpred[q*4+1] = p4.y; vpred[q*4+2] = p4.z; vpred[q*4+3] = p4.w;
    }
    float lmax = -INFINITY;
    u32 kept = 0, mycnt = 0;
    #pragma unroll
    for (int m = 0; m < 16; ++m) {
        lmax = fmaxf(lmax, vpred[m]);
        const u32 j = ((m >> 2) << 11) + (tid << 2) + (m & 3);
        if (minidx[vidx[m]] == j) { kept |= 1u << m; ++mycnt; }
    }

    // ---- P4: block reduce max; block scan of counts -> deterministic slots ----
    #pragma unroll
    for (int off = 32; off > 0; off >>= 1) lmax = fmaxf(lmax, __shfl_down(lmax, off));
    if (lane == 0) scr_f[wave] = lmax;
    u32 xs = mycnt;
    #pragma unroll
    for (int off = 1; off < 64; off <<= 1) { u32 y = __shfl_up(xs, off); if (lane >= off) xs += y; }
    if (lane == 63) scr_u[wave] = xs;
    __syncthreads();                       // B1 (also: minidx reads complete)
    float mx = scr_f[0];
    #pragma unroll
    for (int w = 1; w < NWAVES; ++w) mx = fmaxf(mx, scr_f[w]);
    u32 wb = 0, Ktot = 0;
    #pragma unroll
    for (int w = 0; w < NWAVES; ++w) { const u32 c = scr_u[w]; if (w < wave) wb += c; Ktot += c; }
    const int K = (int)Ktot;
    u32 slot = wb + xs - mycnt;
    // pad-init arr (overwrites minidx alias; all minidx reads done at B1)
    #pragma unroll
    for (int i = 0; i < 8; ++i) arr[(i << 9) + tid] = 0x00FFFFFF00000000ULL;
    __syncthreads();                       // B2

    // ---- P5: gather kept items, packed (key24<<32 | exp_bits) ----
    float psum = 0.f;
    #pragma unroll
    for (int q = 0; q < 4; ++q) {
        float4 r4 = *reinterpret_cast<const float4*>(row_rt + (q << 11) + (tid << 2));
        float rr[4] = { r4.x, r4.y, r4.z, r4.w };
        #pragma unroll
        for (int r = 0; r < 4; ++r) {
            const int m = q*4 + r;
            if (kept & (1u << m)) {
                const float p = vpred[m];
                psum += p;
                const float e = __expf(p - mx);
                u32 u = (u32)(rr[r] * 16777216.0f);   // exact: rt = k*2^-23 -> u = 2k
                u = u > 0xFFFFFEu ? 0xFFFFFEu : u;    // keep strictly < pad key 0xFFFFFF
                const u32 s = slot++;
                arr[((s & 7u) << 9) | (s >> 3)] = ((u64)u << 32) | (u64)__float_as_uint(e);
            }
        }
    }
    #pragma unroll
    for (int off = 32; off > 0; off >>= 1) psum += __shfl_down(psum, off);
    if (lane == 0) scr_f2[wave] = psum;
    __syncthreads();                       // B3
    float sumpred = 0.f;
    #pragma unroll
    for (int w = 0; w < NWAVES; ++w) sumpred += scr_f2[w];

    // ---- readback into registers: thread owns v = 8*tid + i, phys (i<<9)|tid ----
    u64 kv[8];
    #pragma unroll
    for (int i = 0; i < 8; ++i) kv[i] = arr[(i << 9) + tid];

    // ---- 6 register-resident stable LSD radix passes (4-bit digits, key bits 32..55) ----
    for (int sh = 32; sh < 56; sh += 4) {
        // count: nibble-packed per-thread counters (max count 8 fits 4 bits)
        u32 dig = 0, pri = 0; u64 cnt = 0;
        #pragma unroll
        for (int i = 0; i < 8; ++i) {
            const u32 d = (u32)(kv[i] >> sh) & 15u;
            dig |= d << (4*i);
            pri |= ((u32)(cnt >> (4*d)) & 15u) << (4*i);
            cnt += 1ull << (4*d);
        }
        #pragma unroll
        for (int d = 0; d < 16; ++d)
            hist[(d << 9) + tid] = (u16)((cnt >> (4*d)) & 15u);
        __syncthreads();                   // A
        // scan 8192 u16 in linear (digit-major, thread-minor) order
        uint4* h4 = reinterpret_cast<uint4*>(hist);
        const uint4 ha = h4[2*tid], hb = h4[2*tid+1];
        u32 w0[8] = { ha.x, ha.y, ha.z, ha.w, hb.x, hb.y, hb.z, hb.w };
        u32 runc = 0, exv[16];
        #pragma unroll
        for (int i = 0; i < 8; ++i) {
            const u32 lo = w0[i] & 0xFFFFu, hi = w0[i] >> 16;
            exv[2*i]   = runc; runc += lo;
            exv[2*i+1] = runc; runc += hi;
        }
        u32 xc = runc;
        #pragma unroll
        for (int off = 1; off < 64; off <<= 1) { u32 y = __shfl_up(xc, off); if (lane >= off) xc += y; }
        if (lane == 63) scr_u[wave] = xc;
        __syncthreads();                   // B
        u32 cb = xc - runc;
        #pragma unroll
        for (int w = 0; w < NWAVES; ++w) if (w < wave) cb += scr_u[w];
        #pragma unroll
        for (int i = 0; i < 8; ++i)
            w0[i] = ((exv[2*i] + cb) & 0xFFFFu) | ((exv[2*i+1] + cb) << 16);
        h4[2*tid]   = make_uint4(w0[0], w0[1], w0[2], w0[3]);
        h4[2*tid+1] = make_uint4(w0[4], w0[5], w0[6], w0[7]);
        __syncthreads();                   // C
        // scatter
        #pragma unroll
        for (int i = 0; i < 8; ++i) {
            const u32 d = (dig >> (4*i)) & 15u;
            const u32 pos = (u32)hist[(d << 9) + tid] + ((pri >> (4*i)) & 15u);
            arr[((pos & 7u) << 9) | (pos >> 3)] = kv[i];
        }
        __syncthreads();                   // D
        #pragma unroll
        for (int i = 0; i < 8; ++i) kv[i] = arr[(i << 9) + tid];
    }

    // ---- final: prefix sum of exps in sorted order; sum of logs ----
    float vals[8]; float runf = 0.f;
    #pragma unroll
    for (int i = 0; i < 8; ++i) { runf += __uint_as_float((u32)kv[i]); vals[i] = runf; }
    float xf = runf;
    #pragma unroll
    for (int off = 1; off < 64; off <<= 1) { const float y = __shfl_up(xf, off); if (lane >= off) xf += y; }
    if (lane == 63) scr_f[wave] = xf;
    __syncthreads();                       // E
    float excl = xf - runf;
    #pragma unroll
    for (int w = 0; w < NWAVES; ++w) if (w < wave) excl += scr_f[w];
    float logacc = 0.f;
    #pragma unroll
    for (int i = 0; i < 8; ++i) {
        if (tid*8 + i < K) logacc += __logf(excl + vals[i] + EPSF);
    }
    #pragma unroll
    for (int off = 32; off > 0; off >>= 1) logacc += __shfl_down(logacc, off);
    if (lane == 0) scr_f2[wave] = logacc;
    __syncthreads();                       // F
    if (tid == 0) {
        float tot = 0.f;
        #pragma unroll
        for (int w = 0; w < NWAVES; ++w) tot += scr_f2[w];
        row_out[row] = tot - sumpred + (float)K * mx;
    }
}

__global__ __launch_bounds__(256) void listmle_finalize(
    const float* __restrict__ row_out, float* __restrict__ out)
{
    __shared__ double red_d[4];
    const int tid = threadIdx.x;
    const int lane = tid & 63, wave = tid >> 6;
    double acc = 0.0;
    for (int r = tid; r < MROWS; r += 256) acc += (double)row_out[r];
    #pragma unroll
    for (int off = 32; off > 0; off >>= 1) acc += __shfl_down(acc, off);
    if (lane == 0) red_d[wave] = acc;
    __syncthreads();
    if (tid == 0) {
        double tot = 0.0;
        for (int w = 0; w < 4; ++w) tot += red_d[w];
        out[0] = (float)(tot / (double)MROWS);
    }
}

extern "C" void kernel_launch(void* const* d_in, const int* in_sizes, int n_in,
                              void* d_out, int out_size, void* d_ws, size_t ws_size,
                              hipStream_t stream) {
    const float* outputs = (const float*)d_in[0];
    const float* runtime = (const float*)d_in[1];
    const int*   idxs    = (const int*)d_in[2];
    float* out = (float*)d_out;
    float* ws  = (float*)d_ws;

    listmle_row_kernel<<<MROWS, BLOCK, 0, stream>>>(outputs, runtime, idxs, ws);
    listmle_finalize<<<1, 256, 0, stream>>>(ws, out);
}

// Round 4
// 30.243 us; speedup vs baseline: 3.9888x; 1.1643x over previous
//
#include <hip/hip_runtime.h>

#define MROWS 512
#define NCOLS 8192
#define NVALS 4096
#define BLOCK 512
#define NW 8
#define EPSF 1e-10f

typedef unsigned int u32;

// transposed layout for scan arrays: logical e -> phys, conflict-free 8-per-thread chunks
__device__ __forceinline__ int TP(int e) { return ((e & 7) << 9) | (e >> 3); }   // e in [0,4096)
// swizzled layout for exp output: scatter-writes spread banks, ownership reads conflict-free
__device__ __forceinline__ int PH(int v) { return ((v & 7) << 9) | ((v >> 3) ^ ((v & 7) << 1)); }

__global__ __launch_bounds__(BLOCK, 4) void listmle_row_kernel(
    const float* __restrict__ outputs,
    const float* __restrict__ runtime,
    const int*   __restrict__ idxs,
    float* __restrict__ row_out)
{
    __shared__ u32 A[NVALS];        // phase1: minidx; phase2: bucket cursors; phase3: expout (PH layout)
    __shared__ u32 C[NVALS + 8];    // bucket counts -> exclusive bases (TP layout); C[4096] = K
    __shared__ u32 KA[NVALS];       // compare keys at bucket-arrival positions (linear)
    __shared__ float sf[NW], sf2[NW], sf3[NW];
    __shared__ u32 su[NW];

    const int tid = threadIdx.x, lane = tid & 63, wave = tid >> 6;
    const int row = blockIdx.x;
    const float* rp = outputs + (size_t)row * NCOLS;
    const float* rr = runtime + (size_t)row * NCOLS;
    const int*   ri = idxs    + (size_t)row * NCOLS;

    // ---- P0: load 16 items/thread; column j(m) = (m>>2)*2048 + tid*4 + (m&3) ----
    int vidx[16]; float vrt[16], vpred[16];
    #pragma unroll
    for (int q = 0; q < 4; ++q) {
        const int b0 = (q << 11) + (tid << 2);
        int4   i4 = *reinterpret_cast<const int4*>(ri + b0);
        float4 r4 = *reinterpret_cast<const float4*>(rr + b0);
        float4 p4 = *reinterpret_cast<const float4*>(rp + b0);
        vidx[q*4+0]=i4.x;  vidx[q*4+1]=i4.y;  vidx[q*4+2]=i4.z;  vidx[q*4+3]=i4.w;
        vrt[q*4+0]=r4.x;   vrt[q*4+1]=r4.y;   vrt[q*4+2]=r4.z;   vrt[q*4+3]=r4.w;
        vpred[q*4+0]=p4.x; vpred[q*4+1]=p4.y; vpred[q*4+2]=p4.z; vpred[q*4+3]=p4.w;
    }
    #pragma unroll
    for (int i = 0; i < 8; ++i) { A[(i << 9) + tid] = 0xFFFFFFFFu; C[(i << 9) + tid] = 0u; }
    if (tid < 8) C[NVALS + tid] = 0u;
    __syncthreads();                                   // B1

    // ---- P1: dedup — first occurrence (min column) per value ----
    #pragma unroll
    for (int m = 0; m < 16; ++m) {
        const u32 j = ((m >> 2) << 11) + (tid << 2) + (m & 3);
        atomicMin(&A[vidx[m]], j);
    }
    __syncthreads();                                   // B2

    // ---- P2: kept mask; bucket counts; max over all preds ----
    float lmax = -INFINITY;
    u32 kept = 0;
    #pragma unroll
    for (int m = 0; m < 16; ++m) {
        lmax = fmaxf(lmax, vpred[m]);
        const u32 j = ((m >> 2) << 11) + (tid << 2) + (m & 3);
        if (A[vidx[m]] == j) {
            kept |= 1u << m;
            u32 rt24 = (u32)(vrt[m] * 16777216.0f);    // exact monotone 24-bit key
            rt24 = rt24 > 0xFFFFFFu ? 0xFFFFFFu : rt24;
            atomicAdd(&C[TP((int)(rt24 >> 12))], 1u);
        }
    }
    #pragma unroll
    for (int off = 32; off > 0; off >>= 1) lmax = fmaxf(lmax, __shfl_down(lmax, off));
    if (lane == 0) sf[wave] = lmax;
    __syncthreads();                                   // B3
    float mx = sf[0];
    #pragma unroll
    for (int w = 1; w < NW; ++w) mx = fmaxf(mx, sf[w]);

    // ---- P4: block exclusive scan of 4096 bucket counts (8/thread, TP layout) ----
    u32 c8[8], lsum = 0;
    #pragma unroll
    for (int i = 0; i < 8; ++i) { c8[i] = C[(i << 9) + tid]; lsum += c8[i]; }
    u32 xs = lsum;
    #pragma unroll
    for (int off = 1; off < 64; off <<= 1) { u32 y = __shfl_up(xs, off); if (lane >= off) xs += y; }
    if (lane == 63) su[wave] = xs;
    __syncthreads();                                   // B4
    u32 run = xs - lsum, K = 0;
    #pragma unroll
    for (int w = 0; w < NW; ++w) { const u32 t = su[w]; if (w < wave) run += t; K += t; }
    #pragma unroll
    for (int i = 0; i < 8; ++i) { const u32 c = c8[i]; C[(i << 9) + tid] = run; run += c; }
    #pragma unroll
    for (int i = 0; i < 8; ++i) A[(i << 9) + tid] = 0u;          // zero bucket cursors
    if (tid == 0) C[NVALS] = K;                                   // sentinel base
    __syncthreads();                                   // B5

    // ---- P5: scatter compare-keys by atomic arrival within bucket; psum of kept preds ----
    float psum = 0.f;
    u32 sc[16];
    #pragma unroll
    for (int m = 0; m < 16; ++m) {
        if (kept & (1u << m)) {
            psum += vpred[m];
            const u32 j = ((m >> 2) << 11) + (tid << 2) + (m & 3);
            u32 rt24 = (u32)(vrt[m] * 16777216.0f);
            rt24 = rt24 > 0xFFFFFFu ? 0xFFFFFFu : rt24;
            const int b = (int)(rt24 >> 12);
            const u32 base = C[TP(b)];
            const u32 ra = atomicAdd(&A[b], 1u);
            const u32 pos = base + ra;
            KA[pos] = ((rt24 & 0xFFFu) << 13) | j;     // unique key: (low12, column)
            sc[m] = pos;
        }
    }
    #pragma unroll
    for (int off = 32; off > 0; off >>= 1) psum += __shfl_down(psum, off);
    if (lane == 0) sf2[wave] = psum;
    __syncthreads();                                   // B6

    // ---- P6a: deterministic rank within bucket by counting smaller keys ----
    #pragma unroll
    for (int m = 0; m < 16; ++m) {
        if (kept & (1u << m)) {
            const u32 j = ((m >> 2) << 11) + (tid << 2) + (m & 3);
            u32 rt24 = (u32)(vrt[m] * 16777216.0f);
            rt24 = rt24 > 0xFFFFFFu ? 0xFFFFFFu : rt24;
            const int b = (int)(rt24 >> 12);
            const u32 base = C[TP(b)];
            const u32 lim  = C[b == (NVALS - 1) ? NVALS : TP(b + 1)];
            const u32 ck = ((rt24 & 0xFFFu) << 13) | j;
            u32 cr = 0;
            for (u32 q = base; q < lim; ++q) cr += (KA[q] < ck) ? 1u : 0u;
            sc[m] = base + cr;                          // final sorted position
        }
    }
    __syncthreads();                                   // B7 (KA reads + cursor use done)
    #pragma unroll
    for (int i = 0; i < 8; ++i) A[(i << 9) + tid] = 0u;          // zero expout (pads = 0.0f)
    __syncthreads();                                   // B8
    #pragma unroll
    for (int m = 0; m < 16; ++m) {
        if (kept & (1u << m)) {
            const float e = __expf(vpred[m] - mx);
            A[PH((int)sc[m])] = __float_as_uint(e);
        }
    }
    __syncthreads();                                   // B9

    // ---- P7: prefix scan of exps in sorted order; sum of logs ----
    float vals[8], runf = 0.f;
    #pragma unroll
    for (int i = 0; i < 8; ++i) {
        runf += __uint_as_float(A[(i << 9) | (tid ^ (i << 1))]);  // = A[PH(8*tid+i)]
        vals[i] = runf;
    }
    float xf = runf;
    #pragma unroll
    for (int off = 1; off < 64; off <<= 1) { const float y = __shfl_up(xf, off); if (lane >= off) xf += y; }
    if (lane == 63) sf[wave] = xf;
    __syncthreads();                                   // B10
    float excl = xf - runf;
    #pragma unroll
    for (int w = 0; w < NW; ++w) if (w < wave) excl += sf[w];
    float logacc = 0.f;
    #pragma unroll
    for (int i = 0; i < 8; ++i) {
        if ((u32)(tid * 8 + i) < K) logacc += __logf(excl + vals[i] + EPSF);
    }
    #pragma unroll
    for (int off = 32; off > 0; off >>= 1) logacc += __shfl_down(logacc, off);
    if (lane == 0) sf3[wave] = logacc;
    __syncthreads();                                   // B11
    if (tid == 0) {
        float lt = 0.f, pt = 0.f;
        #pragma unroll
        for (int w = 0; w < NW; ++w) { lt += sf3[w]; pt += sf2[w]; }
        row_out[row] = lt - pt + (float)K * mx;
    }
}

__global__ __launch_bounds__(256) void listmle_finalize(
    const float* __restrict__ row_out, float* __restrict__ out)
{
    __shared__ double red_d[4];
    const int tid = threadIdx.x;
    const int lane = tid & 63, wave = tid >> 6;
    double acc = 0.0;
    for (int r = tid; r < MROWS; r += 256) acc += (double)row_out[r];
    #pragma unroll
    for (int off = 32; off > 0; off >>= 1) acc += __shfl_down(acc, off);
    if (lane == 0) red_d[wave] = acc;
    __syncthreads();
    if (tid == 0) {
        double tot = 0.0;
        for (int w = 0; w < 4; ++w) tot += red_d[w];
        out[0] = (float)(tot / (double)MROWS);
    }
}

extern "C" void kernel_launch(void* const* d_in, const int* in_sizes, int n_in,
                              void* d_out, int out_size, void* d_ws, size_t ws_size,
                              hipStream_t stream) {
    const float* outputs = (const float*)d_in[0];
    const float* runtime = (const float*)d_in[1];
    const int*   idxs    = (const int*)d_in[2];
    float* out = (float*)d_out;
    float* ws  = (float*)d_ws;

    listmle_row_kernel<<<MROWS, BLOCK, 0, stream>>>(outputs, runtime, idxs, ws);
    listmle_finalize<<<1, 256, 0, stream>>>(ws, out);
}